// Round 7
// baseline (458.173 us; speedup 1.0000x reference)
//
#include <hip/hip_runtime.h>
#include <math.h>

// Problem dims
#define Mm 8
#define Bb 64
#define Ss 1024
#define Kk 256
#define Hh 8
#define HD 32
#define Ff 1024

typedef _Float16 f16x8 __attribute__((ext_vector_type(8)));
typedef float f32x4 __attribute__((ext_vector_type(4)));

// Workspace layout (float offsets). Lifetimes:
//   Q     [0,131072)        k1->k2     ; then FC16 (k5->k6, 262144 halves)
//   U     [131072,1179648)  k2->k3     ; then GATES (k6b->k7b, 2048 fl)
//   QDB   [1179648,1183744) k2->k3
//   SC16  [1183744,3280896) k3->k4a (4.2M halves) ; then HPART (k7a->k7b)
//   WPART [3280896,7475200) k4a->k5 (4x1048576 fl) ; then H116 (k6->k7a)
#define WS_Q      0u
#define WS_FC16   0u
#define WS_U      131072u
#define WS_GATES  131072u
#define WS_QDB    1179648u
#define WS_SC16   1183744u
#define WS_HPART  1183744u
#define WS_WPART  3280896u
#define WS_H116   3280896u
// total 7475200 floats = 29.9 MB

// ---------------------------------------------------------------------------
// K1: q = q0 @ Wq + bq        (M,B,K)
__global__ __launch_bounds__(256) void k1_qproj(
    const float* __restrict__ q0, const float* __restrict__ wq,
    const float* __restrict__ bq, float* __restrict__ qout) {
  __shared__ float q0s[8 * 260];
  const int m = blockIdx.x, b0 = blockIdx.y * 8, t = threadIdx.x;
#pragma unroll
  for (int j = 0; j < 8; ++j)
    q0s[j * 260 + t] = q0[(m * Bb + b0 + j) * Kk + t];
  __syncthreads();
  float acc[8];
  const float bias = bq[m * Kk + t];
#pragma unroll
  for (int j = 0; j < 8; ++j) acc[j] = bias;
  const float* wcol = wq + m * Kk * Kk + t;
  for (int k4 = 0; k4 < Kk / 4; ++k4) {
    const float w0 = wcol[(k4 * 4 + 0) * Kk];
    const float w1 = wcol[(k4 * 4 + 1) * Kk];
    const float w2 = wcol[(k4 * 4 + 2) * Kk];
    const float w3 = wcol[(k4 * 4 + 3) * Kk];
#pragma unroll
    for (int j = 0; j < 8; ++j) {
      const float4 qv = *(const float4*)&q0s[j * 260 + k4 * 4];
      acc[j] += qv.x * w0 + qv.y * w1 + qv.z * w2 + qv.w * w3;
    }
  }
#pragma unroll
  for (int j = 0; j < 8; ++j)
    qout[(m * Bb + b0 + j) * Kk + t] = acc[j];
}

// ---------------------------------------------------------------------------
// K2: u(m,b,h,k) = sum_d Wk[m,k,h*32+d] * q[m,b,h*32+d]
__global__ __launch_bounds__(256) void k2_uproj(
    const float* __restrict__ wk, const float* __restrict__ bk,
    const float* __restrict__ q, float* __restrict__ u,
    float* __restrict__ qdb) {
  __shared__ float qs[64 * 36];
  const int m = blockIdx.x, h = blockIdx.y, t = threadIdx.x;
#pragma unroll
  for (int p = 0; p < 8; ++p) {
    const int idx = p * 256 + t;
    const int d = idx & 31, b = idx >> 5;
    qs[b * 36 + d] = q[(m * Bb + b) * Kk + h * HD + d];
  }
  __syncthreads();
  float acc[64];
#pragma unroll
  for (int b = 0; b < 64; ++b) acc[b] = 0.f;
  const float* wrow = wk + (m * Kk + t) * Kk + h * HD;
#pragma unroll
  for (int d4 = 0; d4 < 8; ++d4) {
    const float4 w4 = *(const float4*)&wrow[d4 * 4];
#pragma unroll
    for (int b = 0; b < 64; ++b) {
      const float4 q4 = *(const float4*)&qs[b * 36 + d4 * 4];
      acc[b] += q4.x * w4.x + q4.y * w4.y + q4.z * w4.z + q4.w * w4.w;
    }
  }
  for (int b = 0; b < 64; ++b)
    u[((m * Bb + b) * Hh + h) * Kk + t] = acc[b];
  if (t < 64) {
    float s = 0.f;
#pragma unroll
    for (int d = 0; d < 32; ++d)
      s += qs[t * 36 + d] * bk[m * Kk + h * HD + d];
    qdb[(m * Bb + t) * Hh + h] = s;
  }
}

// ---------------------------------------------------------------------------
// K3 (no-LDS MFMA): scores(m,b,h,s) = (key.u + qdb)/sqrt(32), stored fp16.
// grid (64, 16): (b, s-tile of 64). Wave w owns mh rows 16w..16w+15.
// A = u (k-contig, 2 dwordx4/frag), B = key (k-contig, 2 dwordx4/frag).
// No barriers: waves stream independently.
__global__ __launch_bounds__(256) void k3_scores(
    const float* __restrict__ key, const float* __restrict__ u,
    const float* __restrict__ qdb, _Float16* __restrict__ scH) {
  const int b = blockIdx.x, st0 = blockIdx.y * 64, t = threadIdx.x;
  const int w = t >> 6, quad = (t >> 4) & 3, l15 = t & 15;
  const int mh = w * 16 + l15;
  const float* up = u + (((mh >> 3) * Bb + b) * Hh + (mh & 7)) * Kk;
  f32x4 acc[4];
#pragma unroll
  for (int i = 0; i < 4; ++i) acc[i] = (f32x4){0.f, 0.f, 0.f, 0.f};
#pragma unroll
  for (int c = 0; c < 8; ++c) {
    const float* ua = up + c * 32 + quad * 8;
    const float4 a0 = *(const float4*)ua;
    const float4 a1 = *(const float4*)(ua + 4);
    f16x8 af;
    af[0] = (_Float16)a0.x; af[1] = (_Float16)a0.y;
    af[2] = (_Float16)a0.z; af[3] = (_Float16)a0.w;
    af[4] = (_Float16)a1.x; af[5] = (_Float16)a1.y;
    af[6] = (_Float16)a1.z; af[7] = (_Float16)a1.w;
#pragma unroll
    for (int sf = 0; sf < 4; ++sf) {
      const float* kp = key + (size_t)(st0 + sf * 16 + l15) * (Bb * Kk) +
                        b * Kk + c * 32 + quad * 8;
      const float4 b0 = *(const float4*)kp;
      const float4 b1 = *(const float4*)(kp + 4);
      f16x8 bf;
      bf[0] = (_Float16)b0.x; bf[1] = (_Float16)b0.y;
      bf[2] = (_Float16)b0.z; bf[3] = (_Float16)b0.w;
      bf[4] = (_Float16)b1.x; bf[5] = (_Float16)b1.y;
      bf[6] = (_Float16)b1.z; bf[7] = (_Float16)b1.w;
      acc[sf] =
          __builtin_amdgcn_mfma_f32_16x16x32_f16(af, bf, acc[sf], 0, 0, 0);
    }
  }
  const float scale = 0.17677669529663687f;  // 1/sqrt(32)
#pragma unroll
  for (int r = 0; r < 4; ++r) {
    const int mo = w * 16 + quad * 4 + r;
    const size_t row = (size_t)(((mo >> 3) * Bb + b) * Hh + (mo & 7));
    const float qd = qdb[row];
#pragma unroll
    for (int sf = 0; sf < 4; ++sf)
      scH[row * Ss + st0 + sf * 16 + l15] =
          (_Float16)((acc[sf][r] + qd) * scale);
  }
}

// ---------------------------------------------------------------------------
// K3b: softmax over s per (m,b,h) (fp16 in/out) + attn_weights mean-over-h.
// grid (8, 64): 4 waves; wave w handles h = 2w, 2w+1; shuffle-only softmax.
__global__ __launch_bounds__(256) void k3b_softmax(_Float16* __restrict__ scH,
                                                   float* __restrict__ out) {
  __shared__ float rows[8 * 1024];
  const int m = blockIdx.x, b = blockIdx.y, t = threadIdx.x;
  const int w = t >> 6, lane = t & 63;
  const size_t base = (size_t)(m * Bb + b) * (Hh * Ss);
#pragma unroll
  for (int hh = 0; hh < 2; ++hh) {
    const int h = w * 2 + hh;
    _Float16* g = scH + base + h * 1024;
    const f16x8 x0 = *(const f16x8*)&g[lane * 8];
    const f16x8 x1 = *(const f16x8*)&g[512 + lane * 8];
    float v[16];
#pragma unroll
    for (int i = 0; i < 8; ++i) { v[i] = (float)x0[i]; v[8 + i] = (float)x1[i]; }
    float mx = v[0];
#pragma unroll
    for (int i = 1; i < 16; ++i) mx = fmaxf(mx, v[i]);
#pragma unroll
    for (int off = 32; off > 0; off >>= 1)
      mx = fmaxf(mx, __shfl_xor(mx, off, 64));
    float sm = 0.f;
#pragma unroll
    for (int i = 0; i < 16; ++i) { v[i] = __expf(v[i] - mx); sm += v[i]; }
#pragma unroll
    for (int off = 32; off > 0; off >>= 1) sm += __shfl_xor(sm, off, 64);
    const float inv = 1.f / sm;
    f16x8 y0, y1;
#pragma unroll
    for (int i = 0; i < 16; ++i) v[i] *= inv;
#pragma unroll
    for (int i = 0; i < 8; ++i) {
      y0[i] = (_Float16)v[i];
      y1[i] = (_Float16)v[8 + i];
    }
    *(f16x8*)&g[lane * 8] = y0;
    *(f16x8*)&g[512 + lane * 8] = y1;
    float* r = rows + h * 1024;
#pragma unroll
    for (int i = 0; i < 8; ++i) {
      r[lane * 8 + i] = v[i];
      r[512 + lane * 8 + i] = v[8 + i];
    }
  }
  __syncthreads();
#pragma unroll
  for (int p = 0; p < 4; ++p) {
    const int s = p * 256 + t;
    float sum = 0.f;
#pragma unroll
    for (int h = 0; h < 8; ++h) sum += rows[h * 1024 + s];
    out[131072u + (m * Bb + b) * Ss + s] = sum * 0.125f;
  }
}

// ---------------------------------------------------------------------------
// K4a (no-LDS MFMA): partial w(mh,k) over s-quarter.
// grid (64, 4, 4): (b, ko of 64 k, sq of 256 s). A = awH fp16 (s-contig),
// B = value fp32 (k coalesced across lanes). No barriers.
__global__ __launch_bounds__(256) void k4a_av(const float* __restrict__ value,
                                              const _Float16* __restrict__ awH,
                                              float* __restrict__ wpart) {
  const int b = blockIdx.x, ko = blockIdx.y, sq = blockIdx.z, t = threadIdx.x;
  const int w = t >> 6, quad = (t >> 4) & 3, l15 = t & 15;
  const int mh = w * 16 + l15;
  const _Float16* ap =
      awH + ((size_t)((mh >> 3) * Bb + b) * Hh + (mh & 7)) * Ss + sq * 256;
  f32x4 acc[4];
#pragma unroll
  for (int i = 0; i < 4; ++i) acc[i] = (f32x4){0.f, 0.f, 0.f, 0.f};
#pragma unroll
  for (int c = 0; c < 8; ++c) {
    const f16x8 af = *(const f16x8*)&ap[c * 32 + quad * 8];
#pragma unroll
    for (int nf = 0; nf < 4; ++nf) {
      const int k = ko * 64 + nf * 16 + l15;
      f16x8 bf;
#pragma unroll
      for (int j = 0; j < 8; ++j)
        bf[j] = (_Float16)value[(size_t)(sq * 256 + c * 32 + quad * 8 + j) *
                                    (Bb * Kk) +
                                b * Kk + k];
      acc[nf] =
          __builtin_amdgcn_mfma_f32_16x16x32_f16(af, bf, acc[nf], 0, 0, 0);
    }
  }
  float* wp = wpart + sq * 1048576u;
#pragma unroll
  for (int nf = 0; nf < 4; ++nf) {
    const int k = ko * 64 + nf * 16 + l15;
#pragma unroll
    for (int r = 0; r < 4; ++r) {
      const int mo = w * 16 + quad * 4 + r;
      wp[((size_t)((mo >> 3) * Bb + b) * Hh + (mo & 7)) * Kk + k] =
          acc[nf][r];
    }
  }
}

// ---------------------------------------------------------------------------
// K5: w = sum of 4 partials; ctx = w @ Wv_h + bv ; attn_out = ctx @ Wo + bo ;
//     fc_in = relu(concat) stored packed fp16. grid (8, 64): (m, b)
__global__ __launch_bounds__(256) void k5_ctx(
    const float* __restrict__ wv, const float* __restrict__ bv,
    const float* __restrict__ wo, const float* __restrict__ bo,
    const float* __restrict__ s0in, const float* __restrict__ wpart,
    float* __restrict__ attn_out, _Float16* __restrict__ fcH) {
  __shared__ float wsh[2048];
  __shared__ float ctxs[256];
  const int m = blockIdx.x, b = blockIdx.y, t = threadIdx.x;
  const int base = (m * Bb + b) * (Hh * Kk);
#pragma unroll
  for (int p = 0; p < 8; ++p) {
    const int o = base + p * 256 + t;
    wsh[p * 256 + t] = wpart[o] + wpart[1048576u + o] + wpart[2097152u + o] +
                       wpart[3145728u + o];
  }
  __syncthreads();
  const int h = t >> 5;
  float acc = bv[m * Kk + t];
  const float* wvc = wv + m * Kk * Kk + t;
  for (int k4 = 0; k4 < 64; ++k4) {
    const float4 a4 = *(const float4*)&wsh[h * 256 + k4 * 4];
    acc += a4.x * wvc[(k4 * 4 + 0) * Kk] + a4.y * wvc[(k4 * 4 + 1) * Kk] +
           a4.z * wvc[(k4 * 4 + 2) * Kk] + a4.w * wvc[(k4 * 4 + 3) * Kk];
  }
  ctxs[t] = acc;
  __syncthreads();
  float acc2 = bo[m * Kk + t];
  const float* woc = wo + m * Kk * Kk + t;
  for (int k4 = 0; k4 < 64; ++k4) {
    const float4 c4 = *(const float4*)&ctxs[k4 * 4];
    acc2 += c4.x * woc[(k4 * 4 + 0) * Kk] + c4.y * woc[(k4 * 4 + 1) * Kk] +
            c4.z * woc[(k4 * 4 + 2) * Kk] + c4.w * woc[(k4 * 4 + 3) * Kk];
  }
  const int ob = (m * Bb + b) * Kk + t;
  attn_out[ob] = acc2;
  fcH[(m * Bb + b) * 512 + t] = (_Float16)fmaxf(acc2, 0.f);
  fcH[(m * Bb + b) * 512 + 256 + t] = (_Float16)fmaxf(s0in[ob], 0.f);
}

// ---------------------------------------------------------------------------
// K6 (no-LDS MFMA): h1[head] = relu(fc_in @ W1[head] + b1[head]), fp16 out.
// grid (16, 8, 8): (f-tile of 64, m, head). Wave w owns f = ft*64+w*16+l15.
// A = fcH fp16 (1 dwordx4/frag), B = W1 fp32 (8 coalesced dword/frag).
// No barriers.
__global__ __launch_bounds__(256) void k6_mlp1(
    const _Float16* __restrict__ fcH, const float* __restrict__ w1q,
    const float* __restrict__ w1k, const float* __restrict__ w1v,
    const float* __restrict__ w1s, const float* __restrict__ w1g,
    const float* __restrict__ b1q, const float* __restrict__ b1k,
    const float* __restrict__ b1v, const float* __restrict__ b1s,
    const float* __restrict__ b1g, _Float16* __restrict__ h1H) {
  const int ft = blockIdx.x, m = blockIdx.y, head = blockIdx.z,
            t = threadIdx.x;
  const float* w1;
  const float* b1;
  if (head == 0)      { w1 = w1q; b1 = b1q; }
  else if (head == 1) { w1 = w1k; b1 = b1k; }
  else if (head == 2) { w1 = w1v; b1 = b1v; }
  else if (head == 3) { w1 = w1s; b1 = b1s; }
  else {
    w1 = w1g + (size_t)(head - 4) * (Mm * 512 * Ff);
    b1 = b1g + (head - 4) * (Mm * Ff);
  }
  w1 += (size_t)m * 512 * Ff;
  b1 += m * Ff;
  const int w = t >> 6, quad = (t >> 4) & 3, l15 = t & 15;
  const int f = ft * 64 + w * 16 + l15;
  const float* wp = w1 + f;
  const _Float16* ap = fcH + (size_t)m * Bb * 512;
  f32x4 acc[4];
#pragma unroll
  for (int i = 0; i < 4; ++i) acc[i] = (f32x4){0.f, 0.f, 0.f, 0.f};
#pragma unroll
  for (int c = 0; c < 16; ++c) {
    float bw[8];
#pragma unroll
    for (int j = 0; j < 8; ++j)
      bw[j] = wp[(size_t)(c * 32 + quad * 8 + j) * Ff];
    f16x8 af[4];
#pragma unroll
    for (int mt = 0; mt < 4; ++mt)
      af[mt] =
          *(const f16x8*)&ap[(mt * 16 + l15) * 512 + c * 32 + quad * 8];
    f16x8 bf;
#pragma unroll
    for (int j = 0; j < 8; ++j) bf[j] = (_Float16)bw[j];
#pragma unroll
    for (int mt = 0; mt < 4; ++mt)
      acc[mt] =
          __builtin_amdgcn_mfma_f32_16x16x32_f16(af[mt], bf, acc[mt], 0, 0, 0);
  }
  const float bias = b1[f];
  _Float16* hb = h1H + (size_t)((head * Mm + m) * Bb) * Ff + f;
#pragma unroll
  for (int mt = 0; mt < 4; ++mt)
#pragma unroll
    for (int r = 0; r < 4; ++r)
      hb[(size_t)(mt * 16 + quad * 4 + r) * Ff] =
          (_Float16)fmaxf(acc[mt][r] + bias, 0.f);
}

// ---------------------------------------------------------------------------
// K6b: gates(g,m,b) = sigmoid(h1[4+g,m,b,:] . g_w2[g,m,:] + g_b2[g,m])
__global__ __launch_bounds__(64) void k6b_gates(
    const _Float16* __restrict__ h1H, const float* __restrict__ gw2,
    const float* __restrict__ gb2, float* __restrict__ gates) {
  const int gm = blockIdx.x, b = blockIdx.y, t = threadIdx.x;
  const int g = gm >> 3, m = gm & 7;
  const _Float16* hrow = h1H + (size_t)(((4 + g) * Mm + m) * Bb + b) * Ff;
  const float* wrow = gw2 + (g * Mm + m) * Ff;
  float s = 0.f;
#pragma unroll
  for (int i = 0; i < 16; ++i)
    s += (float)hrow[t + i * 64] * wrow[t + i * 64];
  for (int off = 32; off > 0; off >>= 1) s += __shfl_down(s, off, 64);
  if (t == 0)
    gates[(g * Mm + m) * Bb + b] =
        1.f / (1.f + __expf(-(s + gb2[g * Mm + m])));
}

// ---------------------------------------------------------------------------
// K7a (no-LDS MFMA): partial head outputs over f-quarter.
// grid (16, 8, 4): (fq*4+ot, m, head). A = h1H fp16, B = w2 fp32. No barriers.
__global__ __launch_bounds__(256) void k7a_mlp2(
    const _Float16* __restrict__ h1H, const float* __restrict__ w2q,
    const float* __restrict__ w2k, const float* __restrict__ w2v,
    const float* __restrict__ w2s, float* __restrict__ hpart) {
  const int ot = blockIdx.x & 3, fq = blockIdx.x >> 2;
  const int m = blockIdx.y, head = blockIdx.z, t = threadIdx.x;
  const float* w2 =
      (head == 0) ? w2q : (head == 1) ? w2k : (head == 2) ? w2v : w2s;
  w2 += (size_t)m * Ff * Kk;
  const int w = t >> 6, quad = (t >> 4) & 3, l15 = t & 15;
  const int o = ot * 64 + w * 16 + l15;
  const float* wp = w2 + (size_t)(fq * 256) * Kk + o;
  const _Float16* ap = h1H + (size_t)((head * Mm + m) * Bb) * Ff + fq * 256;
  f32x4 acc[4];
#pragma unroll
  for (int i = 0; i < 4; ++i) acc[i] = (f32x4){0.f, 0.f, 0.f, 0.f};
#pragma unroll
  for (int c = 0; c < 8; ++c) {
    float bw[8];
#pragma unroll
    for (int j = 0; j < 8; ++j)
      bw[j] = wp[(size_t)(c * 32 + quad * 8 + j) * Kk];
    f16x8 af[4];
#pragma unroll
    for (int mt = 0; mt < 4; ++mt)
      af[mt] =
          *(const f16x8*)&ap[(size_t)(mt * 16 + l15) * Ff + c * 32 + quad * 8];
    f16x8 bf;
#pragma unroll
    for (int j = 0; j < 8; ++j) bf[j] = (_Float16)bw[j];
#pragma unroll
    for (int mt = 0; mt < 4; ++mt)
      acc[mt] =
          __builtin_amdgcn_mfma_f32_16x16x32_f16(af[mt], bf, acc[mt], 0, 0, 0);
  }
  float* hp = hpart + fq * 524288u + (size_t)((head * Mm + m) * Bb) * Kk + o;
#pragma unroll
  for (int mt = 0; mt < 4; ++mt)
#pragma unroll
    for (int r = 0; r < 4; ++r)
      hp[(size_t)(mt * 16 + quad * 4 + r) * Kk] = acc[mt][r];
}

// ---------------------------------------------------------------------------
// K7b: out = gate*tanh(relu(p0+p1+p2+p3+b2)) + (1-gate)*x0
__global__ __launch_bounds__(256) void k7b_final(
    const float* __restrict__ hpart, const float* __restrict__ gates,
    const float* __restrict__ b2q, const float* __restrict__ b2k,
    const float* __restrict__ b2v, const float* __restrict__ b2s,
    const float* __restrict__ q0, const float* __restrict__ k0,
    const float* __restrict__ v0, const float* __restrict__ s0,
    float* __restrict__ out) {
  const int idx = blockIdx.x * 256 + threadIdx.x;
  const int o = idx & 255;
  const int b = (idx >> 8) & 63;
  const int m = (idx >> 14) & 7;
  const int head = idx >> 17;
  const float* b2 = (head == 0) ? b2q : (head == 1) ? b2k
                    : (head == 2) ? b2v : b2s;
  const float* x0 = (head == 0) ? q0 : (head == 1) ? k0
                    : (head == 2) ? v0 : s0;
  const unsigned ooff = (head == 0) ? 786432u
                        : (head == 1) ? 917504u
                        : (head == 2) ? 1048576u : 655360u;
  float v = hpart[idx] + hpart[524288u + idx] + hpart[1048576u + idx] +
            hpart[1572864u + idx] + b2[m * Kk + o];
  v = tanhf(fmaxf(v, 0.f));
  const float g = gates[(head * Mm + m) * Bb + b];
  const float x = x0[(m * Bb + b) * Kk + o];
  out[ooff + (m * Bb + b) * Kk + o] = g * v + (1.f - g) * x;
}

// ---------------------------------------------------------------------------
extern "C" void kernel_launch(void* const* d_in, const int* in_sizes, int n_in,
                              void* d_out, int out_size, void* d_ws,
                              size_t ws_size, hipStream_t stream) {
  (void)in_sizes; (void)n_in; (void)out_size; (void)ws_size;
  const float* s0  = (const float*)d_in[0];
  const float* q0  = (const float*)d_in[1];
  const float* k0  = (const float*)d_in[2];
  const float* v0  = (const float*)d_in[3];
  const float* key = (const float*)d_in[4];
  const float* val = (const float*)d_in[5];
  const float* wq  = (const float*)d_in[6];
  const float* wk  = (const float*)d_in[7];
  const float* wv  = (const float*)d_in[8];
  const float* bqa = (const float*)d_in[9];
  const float* bka = (const float*)d_in[10];
  const float* bva = (const float*)d_in[11];
  const float* wo  = (const float*)d_in[12];
  const float* bo  = (const float*)d_in[13];
  const float* qw1 = (const float*)d_in[14];
  const float* qb1 = (const float*)d_in[15];
  const float* qw2 = (const float*)d_in[16];
  const float* qb2 = (const float*)d_in[17];
  const float* kw1 = (const float*)d_in[18];
  const float* kb1 = (const float*)d_in[19];
  const float* kw2 = (const float*)d_in[20];
  const float* kb2 = (const float*)d_in[21];
  const float* vw1 = (const float*)d_in[22];
  const float* vb1 = (const float*)d_in[23];
  const float* vw2 = (const float*)d_in[24];
  const float* vb2 = (const float*)d_in[25];
  const float* sw1 = (const float*)d_in[26];
  const float* sb1 = (const float*)d_in[27];
  const float* sw2 = (const float*)d_in[28];
  const float* sb2 = (const float*)d_in[29];
  const float* gw1 = (const float*)d_in[30];
  const float* gb1 = (const float*)d_in[31];
  const float* gw2 = (const float*)d_in[32];
  const float* gb2 = (const float*)d_in[33];
  float* ws  = (float*)d_ws;
  float* out = (float*)d_out;
  _Float16* scH = (_Float16*)(ws + WS_SC16);
  _Float16* fcH = (_Float16*)(ws + WS_FC16);
  _Float16* h1H = (_Float16*)(ws + WS_H116);

  k1_qproj<<<dim3(8, 8), 256, 0, stream>>>(q0, wq, bqa, ws + WS_Q);
  k2_uproj<<<dim3(8, 8), 256, 0, stream>>>(wk, bka, ws + WS_Q, ws + WS_U,
                                           ws + WS_QDB);
  k3_scores<<<dim3(64, 16), 256, 0, stream>>>(key, ws + WS_U, ws + WS_QDB,
                                              scH);
  k3b_softmax<<<dim3(8, 64), 256, 0, stream>>>(scH, out);
  k4a_av<<<dim3(64, 4, 4), 256, 0, stream>>>(val, scH, ws + WS_WPART);
  k5_ctx<<<dim3(8, 64), 256, 0, stream>>>(wv, bva, wo, bo, s0, ws + WS_WPART,
                                          out, fcH);
  k6_mlp1<<<dim3(16, 8, 8), 256, 0, stream>>>(fcH, qw1, kw1, vw1, sw1, gw1,
                                              qb1, kb1, vb1, sb1, gb1, h1H);
  k6b_gates<<<dim3(32, 64), 64, 0, stream>>>(h1H, gw2, gb2, ws + WS_GATES);
  k7a_mlp2<<<dim3(16, 8, 4), 256, 0, stream>>>(h1H, qw2, kw2, vw2, sw2,
                                               ws + WS_HPART);
  k7b_final<<<dim3(2048), 256, 0, stream>>>(ws + WS_HPART, ws + WS_GATES, qb2,
                                            kb2, vb2, sb2, q0, k0, v0, s0,
                                            out);
}